// Round 7
// baseline (97.000 us; speedup 1.0000x reference)
//
#include <hip/hip_runtime.h>
#include <math.h>

#define EPS 1e-8f

typedef short bf16x8 __attribute__((ext_vector_type(8)));
typedef float f32x4  __attribute__((ext_vector_type(4)));

// fp32 -> bf16 bits, round-to-nearest-even
__device__ __forceinline__ short f2bf(float f) {
    union { float fv; unsigned u; } v; v.fv = f;
    unsigned r = v.u + 0x7fffu + ((v.u >> 16) & 1u);
    return (short)(r >> 16);
}
__device__ __forceinline__ float bf2f(short s) {
    union { unsigned u; float f; } v;
    v.u = ((unsigned)(unsigned short)s) << 16;
    return v.f;
}
__device__ __forceinline__ bf16x8 pack8(float4 a, float4 b) {
    bf16x8 p;
    p[0] = f2bf(a.x); p[1] = f2bf(a.y); p[2] = f2bf(a.z); p[3] = f2bf(a.w);
    p[4] = f2bf(b.x); p[5] = f2bf(b.y); p[6] = f2bf(b.z); p[7] = f2bf(b.w);
    return p;
}

// ---------------------------------------------------------------------------
// K1: proj + normalize + quaternion-pair expand + X^T bf16 export.
//   q = normalize4(X @ W^T + b)
//   expq[row][head*16 + i*4 + j] = bf16(q_i * q_j)
//   St[which][b][d][m] = bf16(X[b][m][d])   (each block exports its y-slab)
// Tile 32 rows x 64 cols, kt=64, K=256.  grid (32, 4, 2), 256 thr (2x2 waves).
// ---------------------------------------------------------------------------
__global__ __launch_bounds__(256) void proj_expand_kernel(
    const float* __restrict__ vis, const float* __restrict__ txt,
    const float* __restrict__ Wv, const float* __restrict__ bv,
    const float* __restrict__ Wt, const float* __restrict__ bt,
    short* __restrict__ expq, short* __restrict__ St)
{
    const int which = blockIdx.z;
    const float* X    = which == 0 ? vis : txt;
    const float* W    = which == 0 ? Wv : Wt;
    const float* bias = which == 0 ? bv : bt;
    short* Eo = expq + which * 1024 * 1024;     // 1024 rows x 1024

    const int r0 = blockIdx.x * 32;             // global row (b*512 + m)
    const int c0 = blockIdx.y * 64;
    const int t = threadIdx.x, lane = t & 63, wave = t >> 6;
    const int wr = (wave >> 1) * 16, wc = (wave & 1) * 32;
    const int mrow = lane & 15, quad = lane >> 4;

    __shared__ __align__(16) short As[32][72];   // [row][k]
    __shared__ __align__(16) short Bs[64][72];   // [col][k]

    f32x4 acc[2] = {};

    const int srow = t >> 3, skg = t & 7;
    const int kexp = 64 * blockIdx.y;            // the k-slab this block exports

    for (int k0 = 0; k0 < 256; k0 += 64) {
        const float* xp = X + (r0 + srow) * 256 + k0 + 8 * skg;
        float4 xa = *(const float4*)xp, xb = *(const float4*)(xp + 4);
        const float* wp0 = W + (c0 + srow) * 256 + k0 + 8 * skg;
        const float* wp1 = W + (c0 + srow + 32) * 256 + k0 + 8 * skg;
        float4 wa0 = *(const float4*)wp0, wb0 = *(const float4*)(wp0 + 4);
        float4 wa1 = *(const float4*)wp1, wb1 = *(const float4*)(wp1 + 4);
        __syncthreads();
        *(bf16x8*)&As[srow][8 * skg]      = pack8(xa, xb);
        *(bf16x8*)&Bs[srow][8 * skg]      = pack8(wa0, wb0);
        *(bf16x8*)&Bs[srow + 32][8 * skg] = pack8(wa1, wb1);
        __syncthreads();
        #pragma unroll
        for (int kh = 0; kh < 2; ++kh) {
            bf16x8 a  = *(bf16x8*)&As[wr + mrow][32 * kh + 8 * quad];
            bf16x8 b0 = *(bf16x8*)&Bs[wc + mrow][32 * kh + 8 * quad];
            bf16x8 b1 = *(bf16x8*)&Bs[wc + 16 + mrow][32 * kh + 8 * quad];
            acc[0] = __builtin_amdgcn_mfma_f32_16x16x32_bf16(a, b0, acc[0], 0, 0, 0);
            acc[1] = __builtin_amdgcn_mfma_f32_16x16x32_bf16(a, b1, acc[1], 0, 0, 0);
        }
        if (k0 == kexp) {                       // export X^T slab from staged As
            const int kk = t & 63, rg = t >> 6; // rows 8rg..8rg+7, one kk
            bf16x8 p;
            #pragma unroll
            for (int i = 0; i < 8; ++i) p[i] = As[8 * rg + i][kk];
            const int b = r0 >> 9, mb = r0 & 511;
            *(bf16x8*)(St + which * 262144 + b * 131072 +
                       (kexp + kk) * 512 + mb + 8 * rg) = p;
        }
    }

    // ---- epilogue: LDS exchange -> per-thread whole quaternions ----
    __syncthreads();                             // all MFMA/export LDS reads done
    float* fs = (float*)&Bs[0][0];               // 32 x 64 floats, stride 65
    #pragma unroll
    for (int j = 0; j < 2; ++j) {
        const int lcol = wc + 16 * j + mrow;
        const float bb = bias[c0 + lcol];
        #pragma unroll
        for (int reg = 0; reg < 4; ++reg) {
            const int lrow = wr + quad * 4 + reg;
            fs[lrow * 65 + lcol] = acc[j][reg] + bb;
        }
    }
    __syncthreads();
    #pragma unroll
    for (int u = 0; u < 2; ++u) {                // 512 quats, 2 per thread
        const int qid = t + 256 * u;
        const int lrow = qid >> 4, lhq = qid & 15;
        const float* qp = fs + lrow * 65 + 4 * lhq;
        float q0 = qp[0], q1 = qp[1], q2 = qp[2], q3 = qp[3];
        float s = q0 * q0 + q1 * q1 + q2 * q2 + q3 * q3;
        float inv = 1.f / (sqrtf(s) + EPS);
        q0 *= inv; q1 *= inv; q2 *= inv; q3 *= inv;
        const float qc[4] = {q0, q1, q2, q3};
        bf16x8 pa, pb;
        #pragma unroll
        for (int i = 0; i < 2; ++i)
            #pragma unroll
            for (int jj = 0; jj < 4; ++jj) pa[4 * i + jj] = f2bf(qc[i] * qc[jj]);
        #pragma unroll
        for (int i = 0; i < 2; ++i)
            #pragma unroll
            for (int jj = 0; jj < 4; ++jj) pb[4 * i + jj] = f2bf(qc[2 + i] * qc[jj]);
        short* dst = Eo + (r0 + lrow) * 1024 + (16 * blockIdx.y + lhq) * 16;
        *(bf16x8*)dst       = pa;
        *(bf16x8*)(dst + 8) = pb;
    }
}

// ---------------------------------------------------------------------------
// K2: E[n][m] = exp(dot(expv_n, expt_m)/1024)  (logits in [0,1/16] -> no max
// needed), bf16; plus partial row sums rs[row][16] (one per 32-col slab).
// Tile 32(n) x 64(m), kt=64, K=1024.  grid (16, 8, 2).
// ---------------------------------------------------------------------------
__global__ __launch_bounds__(256) void logits_kernel(
    const short* __restrict__ expq, short* __restrict__ E,
    float* __restrict__ rs)
{
    const int b  = blockIdx.z;
    const int r0 = blockIdx.x * 32;
    const int c0 = blockIdx.y * 64;
    const int t = threadIdx.x, lane = t & 63, wave = t >> 6;
    const int wr = (wave >> 1) * 16, wc = (wave & 1) * 32;
    const int mrow = lane & 15, quad = lane >> 4;

    __shared__ __align__(16) short As[32][72];
    __shared__ __align__(16) short Bs[64][72];

    const short* Abase = expq + (b * 512 + r0) * 1024;
    const short* Bbase = expq + (1024 + b * 512 + c0) * 1024;

    f32x4 acc[2] = {};
    const int srow = t >> 3, skg = t & 7;
    for (int k0 = 0; k0 < 1024; k0 += 64) {
        bf16x8 av  = *(const bf16x8*)(Abase + srow * 1024 + k0 + 8 * skg);
        bf16x8 b0v = *(const bf16x8*)(Bbase + srow * 1024 + k0 + 8 * skg);
        bf16x8 b1v = *(const bf16x8*)(Bbase + (srow + 32) * 1024 + k0 + 8 * skg);
        __syncthreads();
        *(bf16x8*)&As[srow][8 * skg]      = av;
        *(bf16x8*)&Bs[srow][8 * skg]      = b0v;
        *(bf16x8*)&Bs[srow + 32][8 * skg] = b1v;
        __syncthreads();
        #pragma unroll
        for (int kh = 0; kh < 2; ++kh) {
            bf16x8 a  = *(bf16x8*)&As[wr + mrow][32 * kh + 8 * quad];
            bf16x8 b0 = *(bf16x8*)&Bs[wc + mrow][32 * kh + 8 * quad];
            bf16x8 b1 = *(bf16x8*)&Bs[wc + 16 + mrow][32 * kh + 8 * quad];
            acc[0] = __builtin_amdgcn_mfma_f32_16x16x32_bf16(a, b0, acc[0], 0, 0, 0);
            acc[1] = __builtin_amdgcn_mfma_f32_16x16x32_bf16(a, b1, acc[1], 0, 0, 0);
        }
    }

    float e[2][4];
    #pragma unroll
    for (int j = 0; j < 2; ++j)
        #pragma unroll
        for (int reg = 0; reg < 4; ++reg)
            e[j][reg] = __expf(acc[j][reg] * (1.f / 1024.f));

    #pragma unroll
    for (int j = 0; j < 2; ++j) {
        const int col = c0 + wc + 16 * j + mrow;
        #pragma unroll
        for (int reg = 0; reg < 4; ++reg) {
            const int row = r0 + wr + quad * 4 + reg;
            E[(b * 512 + row) * 512 + col] = f2bf(e[j][reg]);
        }
    }
    #pragma unroll
    for (int reg = 0; reg < 4; ++reg) {
        float p = e[0][reg] + e[1][reg];
        p += __shfl_xor(p, 1, 64);
        p += __shfl_xor(p, 2, 64);
        p += __shfl_xor(p, 4, 64);
        p += __shfl_xor(p, 8, 64);
        if (mrow == 0) {
            const int row = r0 + wr + quad * 4 + reg;
            rs[(b * 512 + row) * 16 + (c0 >> 5) + (wc >> 5)] = p;
        }
    }
}

// ---------------------------------------------------------------------------
// K3: out = base + h * normalized attention product.
// which=0: out_v[n][d] = vis + h*rinv_n * sum_m E[n][m]*txt[m][d]
// which=1: out_t[m][d] = txt + h * sum_n (E[n][m]*rinv_n)*vis[n][d]
// B operand from St (bf16, already [d][k]) — direct row copies, no transpose.
// Tile 32 x 64(d), kt=64, K=512.  grid (16, 4, 4) = (row, d, b + 2*which).
// ---------------------------------------------------------------------------
__global__ __launch_bounds__(256) void out_kernel(
    const float* __restrict__ vis, const float* __restrict__ txt,
    const short* __restrict__ E, const float* __restrict__ rs,
    const short* __restrict__ St, const float* __restrict__ hptr,
    float* __restrict__ outv, float* __restrict__ outt)
{
    const int z = blockIdx.z;
    const int b = z & 1, which = z >> 1;
    const int r0 = blockIdx.x * 32;
    const int c0 = blockIdx.y * 64;
    const int t = threadIdx.x, lane = t & 63, wave = t >> 6;
    const int wr = (wave >> 1) * 16, wc = (wave & 1) * 32;
    const int mrow = lane & 15, quad = lane >> 4;
    const float hv = hptr[0];

    const short* Eb   = E + b * 512 * 512;
    const short* Sb   = St + (1 - which) * 262144 + b * 131072;  // [d][k]
    const float* base = (which == 0 ? vis : txt) + b * 512 * 256;
    float*       out  = (which == 0 ? outv : outt) + b * 512 * 256;

    __shared__ __align__(16) short As[32][72];
    __shared__ __align__(16) short Bs[64][72];
    __shared__ float rinv_s[512];

    #pragma unroll
    for (int u = 0; u < 2; ++u) {            // 1/rowsum for all 512 rows of b
        const int row = t + 256 * u;
        const float* p = rs + (b * 512 + row) * 16;
        float s = 0.f;
        #pragma unroll
        for (int i = 0; i < 16; ++i) s += p[i];
        rinv_s[row] = 1.f / s;
    }
    __syncthreads();

    f32x4 acc[2] = {};
    const int cB = t >> 2, kgB = t & 3;      // B: row cB, two 8-chunks
    const int rowA = t >> 3, kgA = t & 7;    // A direct (which=0)
    const int nnA = t >> 2, mgA = t & 3;     // A transpose (which=1)

    for (int k0 = 0; k0 < 512; k0 += 64) {
        bf16x8 sb0 = *(const bf16x8*)(Sb + (c0 + cB) * 512 + k0 + 8 * kgB);
        bf16x8 sb1 = *(const bf16x8*)(Sb + (c0 + cB) * 512 + k0 + 8 * kgB + 32);
        bf16x8 arow;
        float af[8];
        if (which == 0) {
            arow = *(const bf16x8*)(Eb + (r0 + rowA) * 512 + k0 + 8 * kgA);
        } else {
            bf16x8 ev = *(const bf16x8*)(Eb + (k0 + nnA) * 512 + r0 + 8 * mgA);
            const float ri = rinv_s[k0 + nnA];
            #pragma unroll
            for (int c = 0; c < 8; ++c) af[c] = bf2f(ev[c]) * ri;
        }
        __syncthreads();
        if (which == 0) {
            *(bf16x8*)&As[rowA][8 * kgA] = arow;
        } else {
            #pragma unroll
            for (int c = 0; c < 8; ++c) As[8 * mgA + c][nnA] = f2bf(af[c]);
        }
        *(bf16x8*)&Bs[cB][8 * kgB]      = sb0;
        *(bf16x8*)&Bs[cB][8 * kgB + 32] = sb1;
        __syncthreads();
        #pragma unroll
        for (int kh = 0; kh < 2; ++kh) {
            bf16x8 a  = *(bf16x8*)&As[wr + mrow][32 * kh + 8 * quad];
            bf16x8 b0 = *(bf16x8*)&Bs[wc + mrow][32 * kh + 8 * quad];
            bf16x8 b1 = *(bf16x8*)&Bs[wc + 16 + mrow][32 * kh + 8 * quad];
            acc[0] = __builtin_amdgcn_mfma_f32_16x16x32_bf16(a, b0, acc[0], 0, 0, 0);
            acc[1] = __builtin_amdgcn_mfma_f32_16x16x32_bf16(a, b1, acc[1], 0, 0, 0);
        }
    }

    #pragma unroll
    for (int j = 0; j < 2; ++j) {
        const int col = c0 + wc + 16 * j + mrow;
        #pragma unroll
        for (int reg = 0; reg < 4; ++reg) {
            const int row = r0 + wr + quad * 4 + reg;
            const float scale = which == 0 ? hv * rinv_s[row] : hv;
            out[row * 256 + col] = fmaf(scale, acc[j][reg], base[row * 256 + col]);
        }
    }
}

// ---------------------------------------------------------------------------
extern "C" void kernel_launch(void* const* d_in, const int* in_sizes, int n_in,
                              void* d_out, int out_size, void* d_ws, size_t ws_size,
                              hipStream_t stream)
{
    const float* vis = (const float*)d_in[0];
    const float* txt = (const float*)d_in[1];
    const float* Wv  = (const float*)d_in[2];
    const float* bv  = (const float*)d_in[3];
    const float* Wt  = (const float*)d_in[4];
    const float* bt  = (const float*)d_in[5];
    const float* h   = (const float*)d_in[6];

    float* outv = (float*)d_out;                  // 2*512*256
    float* outt = (float*)d_out + 2 * 512 * 256;

    short* expq = (short*)d_ws;                   // 2048 x 1024 bf16 (4 MB)
    short* E    = expq + 2048 * 1024;             // 1024 x 512 bf16 (1 MB)
    float* rs   = (float*)(E + 1024 * 512);       // 1024 x 16 fp32 (64 KB)
    short* St   = (short*)(rs + 1024 * 16);       // 2 x 2 x 256 x 512 bf16 (1 MB)

    proj_expand_kernel<<<dim3(32, 4, 2), 256, 0, stream>>>(vis, txt, Wv, bv, Wt, bt, expq, St);
    logits_kernel<<<dim3(16, 8, 2), 256, 0, stream>>>(expq, E, rs);
    out_kernel<<<dim3(16, 4, 4), 256, 0, stream>>>(vis, txt, E, rs, St, h, outv, outt);
}

// Round 8
// 94.763 us; speedup vs baseline: 1.0236x; 1.0236x over previous
//
#include <hip/hip_runtime.h>
#include <math.h>

#define EPS 1e-8f

typedef short bf16x8 __attribute__((ext_vector_type(8)));
typedef short bf16x4 __attribute__((ext_vector_type(4)));
typedef float f32x4  __attribute__((ext_vector_type(4)));

// fp32 -> bf16 bits, round-to-nearest-even
__device__ __forceinline__ short f2bf(float f) {
    union { float fv; unsigned u; } v; v.fv = f;
    unsigned r = v.u + 0x7fffu + ((v.u >> 16) & 1u);
    return (short)(r >> 16);
}
__device__ __forceinline__ float bf2f(short s) {
    union { unsigned u; float f; } v;
    v.u = ((unsigned)(unsigned short)s) << 16;
    return v.f;
}
__device__ __forceinline__ bf16x8 pack8(float4 a, float4 b) {
    bf16x8 p;
    p[0] = f2bf(a.x); p[1] = f2bf(a.y); p[2] = f2bf(a.z); p[3] = f2bf(a.w);
    p[4] = f2bf(b.x); p[5] = f2bf(b.y); p[6] = f2bf(b.z); p[7] = f2bf(b.w);
    return p;
}

// ---------------------------------------------------------------------------
// K1: proj + normalize + FUSED quaternion-pair expand.
// v = normalize4(X @ W^T + b); expq[row][head*16 + i*4 + j] = bf16(q_i * q_j).
// Tile 32 rows x 64 cols, kt=64, K=256 (4 iters).  grid (32, 4, 2), 256 thr.
// Wave = 16x32 C-tile (2x2 wave grid).  C/D layout: col=lane&15, row=quad*4+reg.
// ---------------------------------------------------------------------------
__global__ __launch_bounds__(256) void proj_expand_kernel(
    const float* __restrict__ vis, const float* __restrict__ txt,
    const float* __restrict__ Wv, const float* __restrict__ bv,
    const float* __restrict__ Wt, const float* __restrict__ bt,
    short* __restrict__ expq)
{
    const int which = blockIdx.z;
    const float* X    = which == 0 ? vis : txt;
    const float* W    = which == 0 ? Wv : Wt;
    const float* bias = which == 0 ? bv : bt;
    short* Eo = expq + which * 1024 * 1024;     // 1024 rows x 1024

    const int r0 = blockIdx.x * 32;
    const int c0 = blockIdx.y * 64;
    const int t = threadIdx.x, lane = t & 63, wave = t >> 6;
    const int wr = (wave >> 1) * 16, wc = (wave & 1) * 32;
    const int mrow = lane & 15, quad = lane >> 4;

    __shared__ __align__(16) short As[32][72];   // [row][k]
    __shared__ __align__(16) short Bs[64][72];   // [col][k]

    f32x4 acc[2] = {};

    const int srow = t >> 3, skg = t & 7;
    for (int k0 = 0; k0 < 256; k0 += 64) {
        const float* xp = X + (r0 + srow) * 256 + k0 + 8 * skg;
        float4 xa = *(const float4*)xp, xb = *(const float4*)(xp + 4);
        const float* wp0 = W + (c0 + srow) * 256 + k0 + 8 * skg;
        const float* wp1 = W + (c0 + srow + 32) * 256 + k0 + 8 * skg;
        float4 wa0 = *(const float4*)wp0, wb0 = *(const float4*)(wp0 + 4);
        float4 wa1 = *(const float4*)wp1, wb1 = *(const float4*)(wp1 + 4);
        __syncthreads();
        *(bf16x8*)&As[srow][8 * skg]      = pack8(xa, xb);
        *(bf16x8*)&Bs[srow][8 * skg]      = pack8(wa0, wb0);
        *(bf16x8*)&Bs[srow + 32][8 * skg] = pack8(wa1, wb1);
        __syncthreads();
        #pragma unroll
        for (int kh = 0; kh < 2; ++kh) {
            bf16x8 a  = *(bf16x8*)&As[wr + mrow][32 * kh + 8 * quad];
            bf16x8 b0 = *(bf16x8*)&Bs[wc + mrow][32 * kh + 8 * quad];
            bf16x8 b1 = *(bf16x8*)&Bs[wc + 16 + mrow][32 * kh + 8 * quad];
            acc[0] = __builtin_amdgcn_mfma_f32_16x16x32_bf16(a, b0, acc[0], 0, 0, 0);
            acc[1] = __builtin_amdgcn_mfma_f32_16x16x32_bf16(a, b1, acc[1], 0, 0, 0);
        }
    }

    const int qbase = lane & ~3;                 // 4 lanes holding this quaternion
    #pragma unroll
    for (int j = 0; j < 2; ++j) {
        const int col  = c0 + wc + 16 * j + mrow;
        const float bb = bias[col];
        const int head = col >> 2;
        #pragma unroll
        for (int reg = 0; reg < 4; ++reg) {
            const int row = r0 + wr + quad * 4 + reg;
            float v = acc[j][reg] + bb;
            float s = v * v;
            s += __shfl_xor(s, 1, 64);
            s += __shfl_xor(s, 2, 64);
            float q = v * (1.f / (sqrtf(s) + EPS));
            // ordered components via dynamic-lane shuffles (ds_bpermute)
            float q0 = __shfl(q, qbase + 0, 64);
            float q1 = __shfl(q, qbase + 1, 64);
            float q2 = __shfl(q, qbase + 2, 64);
            float q3 = __shfl(q, qbase + 3, 64);
            bf16x4 p;
            p[0] = f2bf(q * q0); p[1] = f2bf(q * q1);
            p[2] = f2bf(q * q2); p[3] = f2bf(q * q3);
            *(bf16x4*)(Eo + row * 1024 + head * 16 + (col & 3) * 4) = p;
        }
    }
}

// ---------------------------------------------------------------------------
// K2: E[n][m] = exp(dot(expv_n, expt_m)/1024)  (logits in [0,1/16] -> no max
// subtraction needed), bf16; plus partial row sums rs[row][16] (fp32, one per
// 32-col slab).  Tile 32(n) x 64(m), kt=64, K=1024.  grid (16, 8, 2).
// ---------------------------------------------------------------------------
__global__ __launch_bounds__(256) void logits_kernel(
    const short* __restrict__ expq, short* __restrict__ E,
    float* __restrict__ rs)
{
    const int b  = blockIdx.z;
    const int r0 = blockIdx.x * 32;
    const int c0 = blockIdx.y * 64;
    const int t = threadIdx.x, lane = t & 63, wave = t >> 6;
    const int wr = (wave >> 1) * 16, wc = (wave & 1) * 32;
    const int mrow = lane & 15, quad = lane >> 4;

    __shared__ __align__(16) short As[32][72];
    __shared__ __align__(16) short Bs[64][72];

    const short* Abase = expq + (b * 512 + r0) * 1024;
    const short* Bbase = expq + (1024 + b * 512 + c0) * 1024;

    f32x4 acc[2] = {};
    const int srow = t >> 3, skg = t & 7;
    for (int k0 = 0; k0 < 1024; k0 += 64) {
        bf16x8 av  = *(const bf16x8*)(Abase + srow * 1024 + k0 + 8 * skg);
        bf16x8 b0v = *(const bf16x8*)(Bbase + srow * 1024 + k0 + 8 * skg);
        bf16x8 b1v = *(const bf16x8*)(Bbase + (srow + 32) * 1024 + k0 + 8 * skg);
        __syncthreads();
        *(bf16x8*)&As[srow][8 * skg]      = av;
        *(bf16x8*)&Bs[srow][8 * skg]      = b0v;
        *(bf16x8*)&Bs[srow + 32][8 * skg] = b1v;
        __syncthreads();
        #pragma unroll
        for (int kh = 0; kh < 2; ++kh) {
            bf16x8 a  = *(bf16x8*)&As[wr + mrow][32 * kh + 8 * quad];
            bf16x8 b0 = *(bf16x8*)&Bs[wc + mrow][32 * kh + 8 * quad];
            bf16x8 b1 = *(bf16x8*)&Bs[wc + 16 + mrow][32 * kh + 8 * quad];
            acc[0] = __builtin_amdgcn_mfma_f32_16x16x32_bf16(a, b0, acc[0], 0, 0, 0);
            acc[1] = __builtin_amdgcn_mfma_f32_16x16x32_bf16(a, b1, acc[1], 0, 0, 0);
        }
    }

    float e[2][4];
    #pragma unroll
    for (int j = 0; j < 2; ++j)
        #pragma unroll
        for (int reg = 0; reg < 4; ++reg)
            e[j][reg] = __expf(acc[j][reg] * (1.f / 1024.f));

    #pragma unroll
    for (int j = 0; j < 2; ++j) {
        const int col = c0 + wc + 16 * j + mrow;
        #pragma unroll
        for (int reg = 0; reg < 4; ++reg) {
            const int row = r0 + wr + quad * 4 + reg;
            E[(b * 512 + row) * 512 + col] = f2bf(e[j][reg]);
        }
    }
    // partial sums over this wave's 32 cols -> rs[row][c0/32 + wc/32]
    #pragma unroll
    for (int reg = 0; reg < 4; ++reg) {
        float p = e[0][reg] + e[1][reg];
        p += __shfl_xor(p, 1, 64);
        p += __shfl_xor(p, 2, 64);
        p += __shfl_xor(p, 4, 64);
        p += __shfl_xor(p, 8, 64);
        if (mrow == 0) {
            const int row = r0 + wr + quad * 4 + reg;
            rs[(b * 512 + row) * 16 + (c0 >> 5) + (wc >> 5)] = p;
        }
    }
}

// ---------------------------------------------------------------------------
// K3: out = base + h * softmax-normalized attention product.
// which=0: out_v[n][d] = vis + h*rinv_n * sum_m E[n][m]*txt[m][d]
//          (rinv applied in EPILOGUE - A staged raw)
// which=1: out_t[m][d] = txt + h * sum_n (E[n][m]*rinv_n)*vis[n][d]
//          (rinv applied during transpose-STAGING - per-k scale)
// rinv computed in prologue from rs partials.  Tile 32 x 64(d), kt=64, K=512.
// grid (16, 4, 4) = (row-tile, d-tile, b + 2*which).
// ---------------------------------------------------------------------------
__global__ __launch_bounds__(256) void out_kernel(
    const float* __restrict__ vis, const float* __restrict__ txt,
    const short* __restrict__ E, const float* __restrict__ rs,
    const float* __restrict__ hptr,
    float* __restrict__ outv, float* __restrict__ outt)
{
    const int z = blockIdx.z;
    const int b = z & 1, which = z >> 1;
    const int r0 = blockIdx.x * 32;
    const int c0 = blockIdx.y * 64;
    const int t = threadIdx.x, lane = t & 63, wave = t >> 6;
    const int wr = (wave >> 1) * 16, wc = (wave & 1) * 32;
    const int mrow = lane & 15, quad = lane >> 4;
    const float hv = hptr[0];

    const short* Eb   = E + b * 512 * 512;
    const float* S    = (which == 0 ? txt : vis) + b * 512 * 256;
    const float* base = (which == 0 ? vis : txt) + b * 512 * 256;
    float*       out  = (which == 0 ? outv : outt) + b * 512 * 256;

    __shared__ __align__(16) short As[32][72];
    __shared__ __align__(16) short Bs[64][72];
    __shared__ float rinv_s[512];

    #pragma unroll
    for (int u = 0; u < 2; ++u) {            // 1/rowsum for all 512 rows of b
        const int row = t + 256 * u;
        const float* p = rs + (b * 512 + row) * 16;
        float s = 0.f;
        #pragma unroll
        for (int i = 0; i < 16; ++i) s += p[i];
        rinv_s[row] = 1.f / s;
    }
    __syncthreads();

    f32x4 acc[2] = {};
    const int kkB = t >> 3, cg = t & 7;      // B staging coords
    const int rowA = t >> 3, kgA = t & 7;    // A direct (which=0)
    const int nnA = t >> 2, mgA = t & 3;     // A transpose (which=1)

    for (int k0 = 0; k0 < 512; k0 += 64) {
        float4 sa[2], sb[2];
        #pragma unroll
        for (int u = 0; u < 2; ++u) {
            const float* sp = S + (k0 + kkB + 32 * u) * 256 + c0 + 8 * cg;
            sa[u] = *(const float4*)sp; sb[u] = *(const float4*)(sp + 4);
        }
        bf16x8 arow;
        float af[8];
        if (which == 0) {
            arow = *(const bf16x8*)(Eb + (r0 + rowA) * 512 + k0 + 8 * kgA);
        } else {
            bf16x8 ev = *(const bf16x8*)(Eb + (k0 + nnA) * 512 + r0 + 8 * mgA);
            const float ri = rinv_s[k0 + nnA];
            #pragma unroll
            for (int c = 0; c < 8; ++c) af[c] = bf2f(ev[c]) * ri;
        }
        __syncthreads();
        if (which == 0) {
            *(bf16x8*)&As[rowA][8 * kgA] = arow;
        } else {
            #pragma unroll
            for (int c = 0; c < 8; ++c) As[8 * mgA + c][nnA] = f2bf(af[c]);
        }
        #pragma unroll
        for (int u = 0; u < 2; ++u) {
            const int kk = kkB + 32 * u;
            Bs[8 * cg + 0][kk] = f2bf(sa[u].x);
            Bs[8 * cg + 1][kk] = f2bf(sa[u].y);
            Bs[8 * cg + 2][kk] = f2bf(sa[u].z);
            Bs[8 * cg + 3][kk] = f2bf(sa[u].w);
            Bs[8 * cg + 4][kk] = f2bf(sb[u].x);
            Bs[8 * cg + 5][kk] = f2bf(sb[u].y);
            Bs[8 * cg + 6][kk] = f2bf(sb[u].z);
            Bs[8 * cg + 7][kk] = f2bf(sb[u].w);
        }
        __syncthreads();
        #pragma unroll
        for (int kh = 0; kh < 2; ++kh) {
            bf16x8 a  = *(bf16x8*)&As[wr + mrow][32 * kh + 8 * quad];
            bf16x8 b0 = *(bf16x8*)&Bs[wc + mrow][32 * kh + 8 * quad];
            bf16x8 b1 = *(bf16x8*)&Bs[wc + 16 + mrow][32 * kh + 8 * quad];
            acc[0] = __builtin_amdgcn_mfma_f32_16x16x32_bf16(a, b0, acc[0], 0, 0, 0);
            acc[1] = __builtin_amdgcn_mfma_f32_16x16x32_bf16(a, b1, acc[1], 0, 0, 0);
        }
    }

    #pragma unroll
    for (int j = 0; j < 2; ++j) {
        const int col = c0 + wc + 16 * j + mrow;
        #pragma unroll
        for (int reg = 0; reg < 4; ++reg) {
            const int row = r0 + wr + quad * 4 + reg;
            const float scale = which == 0 ? hv * rinv_s[row] : hv;
            out[row * 256 + col] = fmaf(scale, acc[j][reg], base[row * 256 + col]);
        }
    }
}

// ---------------------------------------------------------------------------
extern "C" void kernel_launch(void* const* d_in, const int* in_sizes, int n_in,
                              void* d_out, int out_size, void* d_ws, size_t ws_size,
                              hipStream_t stream)
{
    const float* vis = (const float*)d_in[0];
    const float* txt = (const float*)d_in[1];
    const float* Wv  = (const float*)d_in[2];
    const float* bv  = (const float*)d_in[3];
    const float* Wt  = (const float*)d_in[4];
    const float* bt  = (const float*)d_in[5];
    const float* h   = (const float*)d_in[6];

    float* outv = (float*)d_out;                  // 2*512*256
    float* outt = (float*)d_out + 2 * 512 * 256;

    short* expq = (short*)d_ws;                   // 2048 x 1024 bf16 (4 MB)
    short* E    = expq + 2048 * 1024;             // 1024 x 512 bf16 (1 MB)
    float* rs   = (float*)(E + 1024 * 512);       // 1024 x 16 fp32 (64 KB)

    proj_expand_kernel<<<dim3(32, 4, 2), 256, 0, stream>>>(vis, txt, Wv, bv, Wt, bt, expq);
    logits_kernel<<<dim3(16, 8, 2), 256, 0, stream>>>(expq, E, rs);
    out_kernel<<<dim3(16, 4, 4), 256, 0, stream>>>(vis, txt, E, rs, h, outv, outt);
}